// Round 3
// baseline (1217.518 us; speedup 1.0000x reference)
//
#include <hip/hip_runtime.h>

#define E_EDGES 131072
#define FIN 16
#define FF 32

// ---------------- Gaunt tensor via exact quadrature (matches reference) -------------
__global__ void gaunt_init(float* __restrict__ G) {
    __shared__ double Ys[128][9];
    __shared__ double wq[128];
    const double ct[8] = {
        -0.9602898564975363, -0.7966664774136267, -0.5255324099163290, -0.1834346424956498,
         0.1834346424956498,  0.5255324099163290,  0.7966664774136267,  0.9602898564975363};
    const double wgt[8] = {
        0.1012285362903763, 0.2223810344533745, 0.3137066458778873, 0.3626837833783620,
        0.3626837833783620, 0.3137066458778873, 0.2223810344533745, 0.1012285362903763};
    const double PI = 3.141592653589793238462643383279502884;
    int t = threadIdx.x;
    if (t < 128) {
        int iq = t >> 4, ip = t & 15;
        double c = ct[iq];
        double s = sqrt(1.0 - c * c);
        double phi = (double)ip * (2.0 * PI / 16.0);
        double x = s * cos(phi), y = s * sin(phi), z = c;
        double* Yp = Ys[t];
        Yp[0] = 0.28209479177387814;
        Yp[1] = 0.4886025119029199 * y;
        Yp[2] = 0.4886025119029199 * z;
        Yp[3] = 0.4886025119029199 * x;
        Yp[4] = 1.0925484305920792 * x * y;
        Yp[5] = 1.0925484305920792 * y * z;
        Yp[6] = 0.31539156525252005 * (3.0 * z * z - 1.0);
        Yp[7] = 1.0925484305920792 * x * z;
        Yp[8] = 0.5462742152960396 * (x * x - y * y);
        wq[t] = wgt[iq] * (2.0 * PI / 16.0);
    }
    __syncthreads();
    for (int idx = t; idx < 729; idx += blockDim.x) {
        int a = idx / 81, b = (idx / 9) % 9, cc = idx % 9;
        double sum = 0.0;
        for (int q = 0; q < 128; ++q) sum += wq[q] * Ys[q][a] * Ys[q][b] * Ys[q][cc];
        G[idx] = (float)sum;
    }
}

// ---------------- zero fill ----------------------------------------------------------
__global__ __launch_bounds__(256) void zero_kernel(float* __restrict__ p, size_t n) {
    size_t i = (size_t)blockIdx.x * 256 + threadIdx.x;
    if (i < n) p[i] = 0.f;
}

// ---------------- degree-wise dense embed: (E,9,16) -> (E,9,32) ----------------------
__global__ __launch_bounds__(256) void embed_kernel(
    const float* __restrict__ xin, const float* __restrict__ W0,
    const float* __restrict__ b0, float* __restrict__ X) {
    int tid = threadIdx.x;
    int e = blockIdx.x * 8 + (tid >> 5);
    int f = tid & 31;
    const float* xr = xin + (size_t)e * 144;
    float* Xr = X + (size_t)e * 288;
#pragma unroll
    for (int c = 0; c < 9; ++c) {
        int l = (c == 0) ? 0 : ((c < 4) ? 1 : 2);
        const float* Wl = W0 + l * FIN * FF;
        float acc = (c == 0) ? b0[f] : 0.f;
#pragma unroll
        for (int g = 0; g < FIN; ++g) acc = fmaf(xr[c * FIN + g], Wl[g * FF + f], acc);
        Xr[c * 32 + f] = acc;
    }
}

// ---------------- one Gaunt-product combo -------------------------------------------
template <int L1, int L2, int L3>
__device__ __forceinline__ void combo(const float* __restrict__ Wm,
                                      const float* __restrict__ bm,
                                      const float* __restrict__ rad,  // LDS, 32
                                      const float (&xa)[9], const float (&y9)[9],
                                      const float* __restrict__ gG,   // LDS, 729
                                      float (&out9)[9], int f) {
    constexpr int S[3] = {0, 1, 4};
    constexpr int L[3] = {1, 3, 5};
    constexpr int A0 = S[L1], DA = L[L1];
    constexpr int Q0 = S[L2], DB = L[L2];
    constexpr int C0 = S[L3], DC = L[L3];
    constexpr int cidx = (L1 * 3 + L2) * 3 + L3;
    float coef = bm[cidx * 32 + f];
    const float* W = Wm + cidx * 1024 + f;
#pragma unroll
    for (int b = 0; b < 32; ++b) coef = fmaf(rad[b], W[b * 32], coef);
    float t[DC];
#pragma unroll
    for (int c = 0; c < DC; ++c) t[c] = 0.f;
#pragma unroll
    for (int a = 0; a < DA; ++a) {
#pragma unroll
        for (int b = 0; b < DB; ++b) {
            float p = xa[A0 + a] * y9[Q0 + b];
#pragma unroll
            for (int c = 0; c < DC; ++c)
                t[c] = fmaf(p, gG[(A0 + a) * 81 + (Q0 + b) * 9 + (C0 + c)], t[c]);
        }
    }
#pragma unroll
    for (int c = 0; c < DC; ++c) out9[C0 + c] = fmaf(t[c], coef, out9[C0 + c]);
}

// ---------------- message pass over one f-chunk of width CW --------------------------
// Reads f-slice [h*CW, h*CW+CW) of X (E,9,32); atomically accumulates messages into
// chunk buffer C (E,9,CW). Diagonal in f, so slice h of X may be updated afterwards
// without affecting later chunks.
template <int CW>
__global__ __launch_bounds__(256) void mp_chunk_kernel(
    const float* __restrict__ X, float* __restrict__ C,
    const float* __restrict__ coords,
    const int* __restrict__ dst, const int* __restrict__ src,
    const float* __restrict__ Wm,     // (27,32,32) this step
    const float* __restrict__ bm,     // (27,32)
    const float* __restrict__ Gglob, int h) {
    constexpr int EPB = 256 / CW;     // edges per block
    __shared__ float gG[729];
    __shared__ float rad_s[EPB][32];
    int tid = threadIdx.x;
    for (int i = tid; i < 729; i += 256) gG[i] = Gglob[i];
    int g = tid / CW;          // edge slot within block
    int fc = tid % CW;         // feature within chunk
    int f = h * CW + fc;       // absolute feature
    int e = blockIdx.x * EPB + g;
    int d = dst[e], s = src[e];
    float rx = coords[3 * d + 0] - coords[3 * s + 0];
    float ry = coords[3 * d + 1] - coords[3 * s + 1];
    float rz = coords[3 * d + 2] - coords[3 * s + 2];
    float r = sqrtf(rx * rx + ry * ry + rz * rz + 1e-8f);
    float ux = rx / r, uy = ry / r, uz = rz / r;
    const float c0 = 0.28209479177387814f, c1 = 0.4886025119029199f;
    const float c2 = 1.0925484305920792f, c20 = 0.31539156525252005f, c22 = 0.5462742152960396f;
    float y9[9];
    y9[0] = c0;
    y9[1] = c1 * uy; y9[2] = c1 * uz; y9[3] = c1 * ux;
    y9[4] = c2 * ux * uy; y9[5] = c2 * uy * uz; y9[6] = c20 * (3.f * uz * uz - 1.f);
    y9[7] = c2 * ux * uz; y9[8] = c22 * (ux * ux - uy * uy);
    // radial basis rad[b] = exp(-(r - b*4/31)^2), lanes of this edge cover b cooperatively
    for (int b = fc; b < 32; b += CW) {
        float cb = (float)((double)b * (4.0 / 31.0));
        float dr = r - cb;
        rad_s[g][b] = expf(-dr * dr);
    }
    __syncthreads();

    const float* xs = X + (size_t)s * 288;
    float xa[9];
#pragma unroll
    for (int a = 0; a < 9; ++a) xa[a] = xs[a * 32 + f];
    float out9[9];
#pragma unroll
    for (int c = 0; c < 9; ++c) out9[c] = 0.f;

    const float* rad = rad_s[g];
    combo<0, 0, 0>(Wm, bm, rad, xa, y9, gG, out9, f);
    combo<0, 1, 1>(Wm, bm, rad, xa, y9, gG, out9, f);
    combo<0, 2, 2>(Wm, bm, rad, xa, y9, gG, out9, f);
    combo<1, 0, 1>(Wm, bm, rad, xa, y9, gG, out9, f);
    combo<1, 1, 0>(Wm, bm, rad, xa, y9, gG, out9, f);
    combo<1, 1, 2>(Wm, bm, rad, xa, y9, gG, out9, f);
    combo<1, 2, 1>(Wm, bm, rad, xa, y9, gG, out9, f);
    combo<2, 0, 2>(Wm, bm, rad, xa, y9, gG, out9, f);
    combo<2, 1, 1>(Wm, bm, rad, xa, y9, gG, out9, f);
    combo<2, 2, 0>(Wm, bm, rad, xa, y9, gG, out9, f);
    combo<2, 2, 2>(Wm, bm, rad, xa, y9, gG, out9, f);

    float* cr = C + (size_t)d * (9 * CW);
#pragma unroll
    for (int c = 0; c < 9; ++c) atomicAdd(&cr[c * CW + fc], out9[c]);
}

// ---------------- A[:, :, h-slice] += C; C = 0 ---------------------------------------
template <int CW>
__global__ __launch_bounds__(256) void addzero_kernel(
    float* __restrict__ A, float* __restrict__ C, int h) {
    size_t i = (size_t)blockIdx.x * 256 + threadIdx.x;
    size_t n = (size_t)E_EDGES * 9 * CW;
    if (i >= n) return;
    int fc = (int)(i % CW);
    size_t ec = i / CW;
    int c = (int)(ec % 9);
    size_t e = ec / 9;
    A[e * 288 + c * 32 + h * CW + fc] += C[i];
    C[i] = 0.f;
}

// ---------------- final: dense(32->32) + gate + dense(32->1) ------------------------
__global__ __launch_bounds__(256) void final_kernel(
    const float* __restrict__ X, const float* __restrict__ W1, const float* __restrict__ b1,
    const float* __restrict__ W2, const float* __restrict__ b2, float* __restrict__ out) {
    int tid = threadIdx.x;
    int e = blockIdx.x * 8 + (tid >> 5);
    int f = tid & 31;
    const float* xr = X + (size_t)e * 288;
    float t[9];
#pragma unroll
    for (int c = 0; c < 9; ++c) {
        int l = (c == 0) ? 0 : ((c < 4) ? 1 : 2);
        const float* Wl = W1 + l * FF * FF;
        float acc = (c == 0) ? b1[f] : 0.f;
#pragma unroll
        for (int g2 = 0; g2 < FF; ++g2) acc = fmaf(xr[c * 32 + g2], Wl[g2 * 32 + f], acc);
        t[c] = acc;
    }
    float gate = (t[0] > 0.f) ? 1.f : 0.f;
#pragma unroll
    for (int c = 0; c < 9; ++c) {
        int l = (c == 0) ? 0 : ((c < 4) ? 1 : 2);
        float v = t[c] * gate * W2[l * 32 + f];
#pragma unroll
        for (int off = 16; off; off >>= 1) v += __shfl_xor(v, off, 32);
        if (f == 0) out[(size_t)e * 9 + c] = v + ((c == 0) ? b2[0] : 0.f);
    }
}

// ---------------- per-chunk-width driver --------------------------------------------
template <int CW>
static void run_mp_steps(float* A, float* C, const float* coords, const int* dst,
                         const int* src, const float* Wmp, const float* bmp,
                         const float* G, hipStream_t stream) {
    constexpr int EPB = 256 / CW;
    constexpr int K = 32 / CW;
    size_t cn = (size_t)E_EDGES * 9 * CW;
    int cblocks = (int)((cn + 255) / 256);
    zero_kernel<<<cblocks, 256, 0, stream>>>(C, cn);
    for (int step = 0; step < 2; ++step) {
        const float* Ws = Wmp + step * 27648;
        const float* bs = bmp + step * 864;
        for (int hh = 0; hh < K; ++hh) {
            mp_chunk_kernel<CW><<<E_EDGES / EPB, 256, 0, stream>>>(
                A, C, coords, dst, src, Ws, bs, G, hh);
            addzero_kernel<CW><<<cblocks, 256, 0, stream>>>(A, C, hh);
        }
    }
}

extern "C" void kernel_launch(void* const* d_in, const int* in_sizes, int n_in,
                              void* d_out, int out_size, void* d_ws, size_t ws_size,
                              hipStream_t stream) {
    const float* x_dftb = (const float*)d_in[0];
    const float* coords = (const float*)d_in[1];
    const int* dst = (const int*)d_in[2];
    const int* src = (const int*)d_in[3];
    const float* W0 = (const float*)d_in[4];
    const float* b0 = (const float*)d_in[5];
    const float* Wmp = (const float*)d_in[6];
    const float* bmp = (const float*)d_in[7];
    const float* W1 = (const float*)d_in[8];
    const float* b1 = (const float*)d_in[9];
    const float* W2 = (const float*)d_in[10];
    const float* b2 = (const float*)d_in[11];
    float* out = (float*)d_out;

    size_t abytes = (size_t)E_EDGES * 288 * sizeof(float);  // 151 MB state
    // pick the widest f-chunk that fits: need 4096 + abytes + abytes*CW/32
    int CW = 0;
    for (int w = 32; w >= 1; w >>= 1) {
        if (4096 + abytes + (abytes / 32) * (size_t)w <= ws_size) { CW = w; break; }
    }
    if (CW == 0) {
        // even 156 MB doesn't fit: clean diagnostic fail (absmax == max|ref|), no OOB
        zero_kernel<<<(out_size + 255) / 256, 256, 0, stream>>>(out, (size_t)out_size);
        return;
    }

    char* ws = (char*)d_ws;
    float* G = (float*)ws;              // 729 floats in first 4 KB
    float* A = (float*)(ws + 4096);     // (E,9,32) state
    float* C = (float*)(ws + 4096 + abytes);  // (E,9,CW) chunk accumulator

    int blocks = E_EDGES / 8;

    gaunt_init<<<1, 256, 0, stream>>>(G);
    embed_kernel<<<blocks, 256, 0, stream>>>(x_dftb, W0, b0, A);
    switch (CW) {
        case 32: run_mp_steps<32>(A, C, coords, dst, src, Wmp, bmp, G, stream); break;
        case 16: run_mp_steps<16>(A, C, coords, dst, src, Wmp, bmp, G, stream); break;
        case 8:  run_mp_steps<8>(A, C, coords, dst, src, Wmp, bmp, G, stream); break;
        case 4:  run_mp_steps<4 >(A, C, coords, dst, src, Wmp, bmp, G, stream); break;
        case 2:  run_mp_steps<2 >(A, C, coords, dst, src, Wmp, bmp, G, stream); break;
        default: run_mp_steps<1 >(A, C, coords, dst, src, Wmp, bmp, G, stream); break;
    }
    final_kernel<<<blocks, 256, 0, stream>>>(A, W1, b1, W2, b2, out);
}